// Round 6
// baseline (547.350 us; speedup 1.0000x reference)
//
#include <hip/hip_runtime.h>

#define HW_PIX 12544          // 112*112
#define M_TOTAL 802816        // 64*112*112
#define TILES_PER_B 49        // 12544 / 256
#define NTILE 3136            // 64 * 49
#define EPS_IN 1e-5f

// ws float offsets
#define WS_G8   0             // [8][4096] split gram partials
#define WS_S8   32768         // [8][64]   split channel sums
#define WS_WM   33280         // [4096]
#define WS_BIAS 37376         // [64]
#define WS_SG   37440         // [4096]

typedef __attribute__((ext_vector_type(8))) short bf16x8_t;   // 8 bf16 = 4 VGPR
typedef __attribute__((ext_vector_type(4))) float f32x4_t;

__device__ __forceinline__ unsigned short f2bf(float f) {
  union { float f; unsigned u; } v; v.f = f;
  unsigned r = v.u + 0x7FFFu + ((v.u >> 16) & 1u);   // round-to-nearest-even
  return (unsigned short)(r >> 16);
}

__device__ __forceinline__ float bf2f(unsigned short h) {
  union { unsigned u; float f; } v; v.u = ((unsigned)h) << 16;
  return v.f;
}

// ---------------- Pass 1: gram + sums, direct-from-global MFMA, no staging -----
// Wave w owns pixels [w*256, (w+1)*256). Lane (g,m), k-step ks, block cb loads
// x[ch=cb*16+m][px0+ks*32+8g .. +7] -> bf16x8 frag. A==B construction (gram
// trick) keeps it layout-robust. acc[ra][cb] covers the full 64x64.
__global__ __launch_bounds__(256) void k_gram(const float* __restrict__ x,
                                              float* __restrict__ ws) {
  __shared__ float Gs[64][66];     // +2 pad: 2-way banks on scatter (free)
  __shared__ float ssum_s[64];
  const int t    = threadIdx.x;
  const int lane = t & 63;
  const int wv   = t >> 6;
  const int g    = lane >> 4;
  const int m    = lane & 15;
  const int bx   = blockIdx.x;

  for (int i = t; i < 64 * 66; i += 256) (&Gs[0][0])[i] = 0.f;
  if (t < 64) ssum_s[t] = 0.f;
  __syncthreads();

  const int w   = bx * 4 + wv;            // wave id 0..3135
  const int b   = w / TILES_PER_B;
  const int px0 = (w - b * TILES_PER_B) * 256;
  const float* xb = x + (size_t)(b * 64) * HW_PIX + px0 + 8 * g;

  f32x4_t acc[4][4];
  #pragma unroll
  for (int i = 0; i < 4; ++i)
    #pragma unroll
    for (int j = 0; j < 4; ++j) acc[i][j] = (f32x4_t){0.f, 0.f, 0.f, 0.f};
  float ssum[4] = {0.f, 0.f, 0.f, 0.f};

  #pragma unroll
  for (int ks = 0; ks < 8; ++ks) {
    bf16x8_t f[4];
    #pragma unroll
    for (int cb = 0; cb < 4; ++cb) {
      const float* p = xb + (size_t)(cb * 16 + m) * HW_PIX + ks * 32;
      float4 lo = *(const float4*)p;
      float4 hi = *(const float4*)(p + 4);
      ssum[cb] += (lo.x + lo.y) + (lo.z + lo.w) + (hi.x + hi.y) + (hi.z + hi.w);
      bf16x8_t ff;
      ff[0] = (short)f2bf(lo.x); ff[1] = (short)f2bf(lo.y);
      ff[2] = (short)f2bf(lo.z); ff[3] = (short)f2bf(lo.w);
      ff[4] = (short)f2bf(hi.x); ff[5] = (short)f2bf(hi.y);
      ff[6] = (short)f2bf(hi.z); ff[7] = (short)f2bf(hi.w);
      f[cb] = ff;
    }
    #pragma unroll
    for (int ra = 0; ra < 4; ++ra)
      #pragma unroll
      for (int cbb = 0; cbb < 4; ++cbb)
        acc[ra][cbb] = __builtin_amdgcn_mfma_f32_16x16x32_bf16(f[ra], f[cbb],
                                                               acc[ra][cbb], 0, 0, 0);
  }

  // ---- cross-wave reduce in LDS (ds_add_f32, fire-and-forget)
  // D map (m89-verified): col = lane&15, row = (lane>>4)*4 + reg
  #pragma unroll
  for (int ra = 0; ra < 4; ++ra)
    #pragma unroll
    for (int cbb = 0; cbb < 4; ++cbb)
      #pragma unroll
      for (int rg = 0; rg < 4; ++rg)
        atomicAdd(&Gs[ra * 16 + g * 4 + rg][cbb * 16 + m], acc[ra][cbb][rg]);
  // channel sums: fold g with shuffles, then 4-way LDS atomic per channel
  #pragma unroll
  for (int cb = 0; cb < 4; ++cb) {
    float v = ssum[cb];
    v += __shfl_xor(v, 16, 64);
    v += __shfl_xor(v, 32, 64);
    if (g == 0) atomicAdd(&ssum_s[cb * 16 + m], v);
  }
  __syncthreads();

  float* G8 = ws + WS_G8 + (size_t)(bx & 7) * 4096;
  for (int i = t; i < 4096; i += 256)
    atomicAdd(&G8[i], Gs[i >> 6][i & 63]);
  if (t < 64) atomicAdd(ws + WS_S8 + (bx & 7) * 64 + t, ssum_s[t]);
}

// ---------------- Pass 2: Newton-Schulz on 64x64, single block -----------------
__device__ __forceinline__ void mm_core(float acc[4][4], const float (*X)[68],
                                        const float (*Y)[68], int iB, int jB) {
  #pragma unroll
  for (int a = 0; a < 4; ++a)
    #pragma unroll
    for (int b = 0; b < 4; ++b) acc[a][b] = 0.f;
  #pragma unroll 4
  for (int kq = 0; kq < 16; ++kq) {
    float4 xr[4], yr[4];
    #pragma unroll
    for (int d = 0; d < 4; ++d) {
      xr[d] = *(const float4*)&X[iB + 16 * d][4 * kq];
      yr[d] = *(const float4*)&Y[jB + 16 * d][4 * kq];
    }
    #pragma unroll
    for (int di = 0; di < 4; ++di)
      #pragma unroll
      for (int dj = 0; dj < 4; ++dj)
        acc[di][dj] += xr[di].x * yr[dj].x + xr[di].y * yr[dj].y +
                       xr[di].z * yr[dj].z + xr[di].w * yr[dj].w;
  }
}

__global__ __launch_bounds__(256) void k_ns(float* __restrict__ ws) {
  float* G8   = ws + WS_G8;
  float* S8   = ws + WS_S8;
  float* wm   = ws + WS_WM;
  float* bias = ws + WS_BIAS;
  float* Sg   = ws + WS_SG;
  __shared__ float bufs[3][64][68];
  __shared__ float mean_s[64];
  __shared__ float r_s;
  const int t = threadIdx.x;
  const float inv_m = 1.0f / (float)M_TOTAL;
  if (t < 64) {
    float s = 0.f;
    #pragma unroll
    for (int k = 0; k < 8; ++k) s += S8[k * 64 + t];
    mean_s[t] = s * inv_m;
  }
  __syncthreads();
  for (int idx = t; idx < 4096; idx += 256) {
    int i = idx >> 6, j = idx & 63;
    float g = 0.f;
    #pragma unroll
    for (int k = 0; k < 8; ++k) g += G8[k * 4096 + idx];
    bufs[1][i][j] = g * inv_m - mean_s[i] * mean_s[j] + ((i == j) ? EPS_IN : 0.f);
  }
  __syncthreads();
  if (t == 0) {
    float tr = 0.f;
    for (int i = 0; i < 64; ++i) tr += bufs[1][i][i];
    r_s = 1.0f / tr;
  }
  __syncthreads();
  const float r = r_s;
  for (int idx = t; idx < 4096; idx += 256) {
    int i = idx >> 6, j = idx & 63;
    Sg[idx] = bufs[1][i][j] * r;
    bufs[0][i][j] = (i == j) ? 1.f : 0.f;
  }
  __syncthreads();
  int pa = 0, pb = 1, pc = 2;
  const int iB = t >> 4, jB = t & 15;
  float acc[4][4];
  for (int itn = 0; itn < 5; ++itn) {
    mm_core(acc, (const float(*)[68])bufs[pa], (const float(*)[68])bufs[pa], iB, jB);
    #pragma unroll
    for (int di = 0; di < 4; ++di)
      #pragma unroll
      for (int dj = 0; dj < 4; ++dj)
        bufs[pb][iB + 16 * di][jB + 16 * dj] = acc[di][dj];
    __syncthreads();
    mm_core(acc, (const float(*)[68])bufs[pb], (const float(*)[68])bufs[pa], iB, jB);
    #pragma unroll
    for (int di = 0; di < 4; ++di)
      #pragma unroll
      for (int dj = 0; dj < 4; ++dj)
        bufs[pc][iB + 16 * di][jB + 16 * dj] = acc[di][dj];
    __syncthreads();
    for (int idx = t; idx < 4096; idx += 256)
      bufs[pb][idx >> 6][idx & 63] = Sg[idx];
    __syncthreads();
    mm_core(acc, (const float(*)[68])bufs[pc], (const float(*)[68])bufs[pb], iB, jB);
    __syncthreads();
    #pragma unroll
    for (int di = 0; di < 4; ++di)
      #pragma unroll
      for (int dj = 0; dj < 4; ++dj) {
        int ii = iB + 16 * di, jj = jB + 16 * dj;
        bufs[pc][ii][jj] = 1.5f * bufs[pa][ii][jj] - 0.5f * acc[di][dj];
      }
    __syncthreads();
    int tmp = pa; pa = pc; pc = tmp;
  }
  const float sr = sqrtf(r);
  for (int idx = t; idx < 4096; idx += 256)
    wm[idx] = bufs[pa][idx >> 6][idx & 63] * sr;
  if (t < 64) {
    float a = 0.f;
    for (int k = 0; k < 64; ++k) a += bufs[pa][t][k] * mean_s[k];
    bias[t] = -a * sr;
  }
}

// ---------------- Pass 3: out = wm*x + bias via MFMA, transposed LDS -----------
// K-permutation: position P <-> channel c = 4*(P&15) + (P>>4); A and B both use
// it, so the contraction is exact. wm split hi+lo bf16 -> ~fp32 wm precision.
__global__ __launch_bounds__(256) void k_apply(const float* __restrict__ x,
                                               const float* __restrict__ ws,
                                               float* __restrict__ out) {
  __shared__ unsigned short Y[256][68];   // [pixel][P], row 136 B (8B-aligned)
  const int t    = threadIdx.x;
  const int lane = t & 63;
  const int wv   = t >> 6;
  const int g    = lane >> 4;
  const int m    = lane & 15;
  const int bx   = blockIdx.x;
  const int b    = bx / TILES_PER_B;
  const int p0   = (bx - b * TILES_PER_B) * 256;
  const float* __restrict__ wm   = ws + WS_WM;
  const float* __restrict__ bias = ws + WS_BIAS;

  // ---- A-frags (wm rows, hi/lo split) + bias, in registers
  const int arow = wv * 16 + m;
  bf16x8_t aHi[2], aLo[2];
  #pragma unroll
  for (int ks = 0; ks < 2; ++ks) {
    #pragma unroll
    for (int e = 0; e < 8; ++e) {
      const int P = ks * 32 + g * 8 + e;
      const int c = 4 * (P & 15) + (P >> 4);
      float f = wm[arow * 64 + c];
      unsigned short hi = f2bf(f);
      unsigned short lo = f2bf(f - bf2f(hi));
      aHi[ks][e] = (short)hi;
      aLo[ks][e] = (short)lo;
    }
  }
  float bv[4];
  #pragma unroll
  for (int rr = 0; rr < 4; ++rr) bv[rr] = bias[wv * 16 + g * 4 + rr];

  // ---- stage: thread t owns pixel p0+t, loads 64 channels as scalar dwords
  const size_t gbase = (size_t)(b * 64) * HW_PIX + p0 + t;
  #pragma unroll
  for (int r = 0; r < 4; ++r) {
    float f[16];
    #pragma unroll
    for (int j = 0; j < 16; ++j)
      f[j] = x[gbase + (size_t)(4 * j + r) * HW_PIX];
    #pragma unroll
    for (int q = 0; q < 4; ++q) {
      ushort4 u;
      u.x = f2bf(f[4 * q + 0]); u.y = f2bf(f[4 * q + 1]);
      u.z = f2bf(f[4 * q + 2]); u.w = f2bf(f[4 * q + 3]);
      *(ushort4*)&Y[t][16 * r + 4 * q] = u;   // P = 16r + 4q + e
    }
  }
  __syncthreads();

  // ---- MFMA: wave wv owns out rows [wv*16, wv*16+16), 16 pixel-tiles
  const size_t obase = (size_t)(b * 64) * HW_PIX + p0;
  #pragma unroll 2
  for (int tile = 0; tile < 16; ++tile) {
    const int pcol = tile * 16 + m;
    bf16x8_t bf[2];
    #pragma unroll
    for (int ks = 0; ks < 2; ++ks) {
      union { ushort4 u2[2]; bf16x8_t v; } cu;
      cu.u2[0] = *(const ushort4*)&Y[pcol][ks * 32 + g * 8];
      cu.u2[1] = *(const ushort4*)&Y[pcol][ks * 32 + g * 8 + 4];
      bf[ks] = cu.v;
    }
    f32x4_t acc = (f32x4_t){bv[0], bv[1], bv[2], bv[3]};
    acc = __builtin_amdgcn_mfma_f32_16x16x32_bf16(aHi[0], bf[0], acc, 0, 0, 0);
    acc = __builtin_amdgcn_mfma_f32_16x16x32_bf16(aHi[1], bf[1], acc, 0, 0, 0);
    acc = __builtin_amdgcn_mfma_f32_16x16x32_bf16(aLo[0], bf[0], acc, 0, 0, 0);
    acc = __builtin_amdgcn_mfma_f32_16x16x32_bf16(aLo[1], bf[1], acc, 0, 0, 0);
    // D map: col = lane&15, row = (lane>>4)*4 + reg
    #pragma unroll
    for (int rr = 0; rr < 4; ++rr)
      out[obase + (size_t)(wv * 16 + g * 4 + rr) * HW_PIX + tile * 16 + m] = acc[rr];
  }
}

extern "C" void kernel_launch(void* const* d_in, const int* in_sizes, int n_in,
                              void* d_out, int out_size, void* d_ws, size_t ws_size,
                              hipStream_t stream) {
  const float* x = (const float*)d_in[0];
  float* out = (float*)d_out;
  float* ws  = (float*)d_ws;
  hipMemsetAsync(d_ws, 0, (32768 + 512) * sizeof(float), stream);  // G8 + S8
  k_gram<<<784, 256, 0, stream>>>(x, ws);
  k_ns<<<1, 256, 0, stream>>>(ws);
  k_apply<<<NTILE, 256, 0, stream>>>(x, ws, out);
}

// Round 7
// 452.119 us; speedup vs baseline: 1.2106x; 1.2106x over previous
//
#include <hip/hip_runtime.h>

#define HW_PIX 12544          // 112*112
#define M_TOTAL 802816        // 64*112*112
#define TILES_PER_B 49        // 12544 / 256
#define NTILE 3136            // 64 * 49
#define GRID1 784             // gram: 4 tiles per block
#define EPS_IN 1e-5f

// ws float offsets
#define WS_G8   0             // [8][4096] split gram partials
#define WS_S8   32768         // [8][64]   split channel sums
#define WS_WM   33280         // [4096] (fp32 wm; unused by apply now)
#define WS_BIAS 37376         // [64]
#define WS_SG   37440         // [4096]
#define WS_WMH  41536         // [4096 ushort] = 2048 floats, frag-ordered hi
#define WS_WML  43584         // [4096 ushort] = 2048 floats, frag-ordered lo

typedef __attribute__((ext_vector_type(8))) short bf16x8_t;   // 8 bf16 = 4 VGPR
typedef __attribute__((ext_vector_type(4))) float f32x4_t;

__device__ __forceinline__ unsigned short f2bf(float f) {
  union { float f; unsigned u; } v; v.f = f;
  unsigned r = v.u + 0x7FFFu + ((v.u >> 16) & 1u);   // round-to-nearest-even
  return (unsigned short)(r >> 16);
}

__device__ __forceinline__ float bf2f(unsigned short h) {
  union { unsigned u; float f; } v; v.u = ((unsigned)h) << 16;
  return v.f;
}

// ---------------- Pass 1: per-channel sums + raw gram G = X X^T (bf16 MFMA) ----
// R3-proven staged version: 4 tiles/block, coalesced 1KB wave loads, reg acc.
__global__ __launch_bounds__(256) void k_gram(const float* __restrict__ x,
                                              float* __restrict__ ws) {
  __shared__ unsigned short xs[64][264];
  __shared__ float ps[256];
  const int t    = threadIdx.x;
  const int lane = t & 63;
  const int wv   = t >> 6;
  const int bx   = blockIdx.x;

  f32x4_t acc[4];
  #pragma unroll
  for (int i = 0; i < 4; ++i) acc[i] = (f32x4_t){0.f, 0.f, 0.f, 0.f};
  float csum = 0.f;

  for (int itc = 0; itc < 4; ++itc) {
    const int ci = bx + itc * GRID1;
    const int b  = ci / TILES_PER_B;
    const int p0 = (ci - b * TILES_PER_B) * 256;
    const size_t base = (size_t)(b * 64) * HW_PIX + p0 + 4 * (t & 63);

    #pragma unroll
    for (int h = 0; h < 2; ++h) {
      float4 v[8];
      #pragma unroll
      for (int i = 0; i < 8; ++i) {
        const int c = 4 * (8 * h + i) + wv;
        v[i] = *(const float4*)(x + base + (size_t)c * HW_PIX);
      }
      #pragma unroll
      for (int i = 0; i < 8; ++i) {
        const int c = 4 * (8 * h + i) + wv;
        ushort4 hh;
        hh.x = f2bf(v[i].x); hh.y = f2bf(v[i].y);
        hh.z = f2bf(v[i].z); hh.w = f2bf(v[i].w);
        *(ushort4*)&xs[c][4 * (t & 63)] = hh;
      }
    }
    __syncthreads();

    #pragma unroll
    for (int ks = 0; ks < 8; ++ks) {
      const int col = ks * 32 + 8 * (lane >> 4);
      bf16x8_t fa = *(const bf16x8_t*)&xs[wv * 16 + (lane & 15)][col];
      #pragma unroll
      for (int cb = 0; cb < 4; ++cb) {
        bf16x8_t fb = *(const bf16x8_t*)&xs[cb * 16 + (lane & 15)][col];
        acc[cb] = __builtin_amdgcn_mfma_f32_16x16x32_bf16(fa, fb, acc[cb], 0, 0, 0);
      }
    }

    {
      const int c = t >> 2, q = t & 3;
      #pragma unroll
      for (int j = 0; j < 8; ++j) {
        bf16x8_t u = *(const bf16x8_t*)&xs[c][q * 64 + 8 * j];
        #pragma unroll
        for (int e = 0; e < 8; ++e) csum += bf2f((unsigned short)u[e]);
      }
    }
    __syncthreads();
  }

  ps[t] = csum;
  __syncthreads();
  if (t < 64) {
    float s4 = ps[4 * t] + ps[4 * t + 1] + ps[4 * t + 2] + ps[4 * t + 3];
    atomicAdd(ws + WS_S8 + (bx & 7) * 64 + t, s4);
  }
  float* G8 = ws + WS_G8 + (size_t)(bx & 7) * 4096;
  const int g = lane >> 4, cl = lane & 15;
  #pragma unroll
  for (int cb = 0; cb < 4; ++cb)
    #pragma unroll
    for (int rg = 0; rg < 4; ++rg)
      atomicAdd(&G8[(wv * 16 + g * 4 + rg) * 64 + cb * 16 + cl], acc[cb][rg]);
}

// ---------------- Pass 2: Newton-Schulz on 64x64, single block -----------------
__device__ __forceinline__ void mm_core(float acc[4][4], const float (*X)[68],
                                        const float (*Y)[68], int iB, int jB) {
  #pragma unroll
  for (int a = 0; a < 4; ++a)
    #pragma unroll
    for (int b = 0; b < 4; ++b) acc[a][b] = 0.f;
  #pragma unroll 4
  for (int kq = 0; kq < 16; ++kq) {
    float4 xr[4], yr[4];
    #pragma unroll
    for (int d = 0; d < 4; ++d) {
      xr[d] = *(const float4*)&X[iB + 16 * d][4 * kq];
      yr[d] = *(const float4*)&Y[jB + 16 * d][4 * kq];
    }
    #pragma unroll
    for (int di = 0; di < 4; ++di)
      #pragma unroll
      for (int dj = 0; dj < 4; ++dj)
        acc[di][dj] += xr[di].x * yr[dj].x + xr[di].y * yr[dj].y +
                       xr[di].z * yr[dj].z + xr[di].w * yr[dj].w;
  }
}

__global__ __launch_bounds__(256) void k_ns(float* __restrict__ ws) {
  float* G8   = ws + WS_G8;
  float* S8   = ws + WS_S8;
  float* bias = ws + WS_BIAS;
  float* Sg   = ws + WS_SG;
  unsigned short* wmh = (unsigned short*)(ws + WS_WMH);
  unsigned short* wml = (unsigned short*)(ws + WS_WML);
  __shared__ float bufs[3][64][68];
  __shared__ float mean_s[64];
  __shared__ float r_s;
  const int t = threadIdx.x;
  const float inv_m = 1.0f / (float)M_TOTAL;
  if (t < 64) {
    float s = 0.f;
    #pragma unroll
    for (int k = 0; k < 8; ++k) s += S8[k * 64 + t];
    mean_s[t] = s * inv_m;
  }
  __syncthreads();
  for (int idx = t; idx < 4096; idx += 256) {
    int i = idx >> 6, j = idx & 63;
    float g = 0.f;
    #pragma unroll
    for (int k = 0; k < 8; ++k) g += G8[k * 4096 + idx];
    bufs[1][i][j] = g * inv_m - mean_s[i] * mean_s[j] + ((i == j) ? EPS_IN : 0.f);
  }
  __syncthreads();
  if (t == 0) {
    float tr = 0.f;
    for (int i = 0; i < 64; ++i) tr += bufs[1][i][i];
    r_s = 1.0f / tr;
  }
  __syncthreads();
  const float r = r_s;
  for (int idx = t; idx < 4096; idx += 256) {
    int i = idx >> 6, j = idx & 63;
    Sg[idx] = bufs[1][i][j] * r;
    bufs[0][i][j] = (i == j) ? 1.f : 0.f;
  }
  __syncthreads();
  int pa = 0, pb = 1, pc = 2;
  const int iB = t >> 4, jB = t & 15;
  float acc[4][4];
  for (int itn = 0; itn < 5; ++itn) {
    mm_core(acc, (const float(*)[68])bufs[pa], (const float(*)[68])bufs[pa], iB, jB);
    #pragma unroll
    for (int di = 0; di < 4; ++di)
      #pragma unroll
      for (int dj = 0; dj < 4; ++dj)
        bufs[pb][iB + 16 * di][jB + 16 * dj] = acc[di][dj];
    __syncthreads();
    mm_core(acc, (const float(*)[68])bufs[pb], (const float(*)[68])bufs[pa], iB, jB);
    #pragma unroll
    for (int di = 0; di < 4; ++di)
      #pragma unroll
      for (int dj = 0; dj < 4; ++dj)
        bufs[pc][iB + 16 * di][jB + 16 * dj] = acc[di][dj];
    __syncthreads();
    for (int idx = t; idx < 4096; idx += 256)
      bufs[pb][idx >> 6][idx & 63] = Sg[idx];
    __syncthreads();
    mm_core(acc, (const float(*)[68])bufs[pc], (const float(*)[68])bufs[pb], iB, jB);
    __syncthreads();
    #pragma unroll
    for (int di = 0; di < 4; ++di)
      #pragma unroll
      for (int dj = 0; dj < 4; ++dj) {
        int ii = iB + 16 * di, jj = jB + 16 * dj;
        bufs[pc][ii][jj] = 1.5f * bufs[pa][ii][jj] - 0.5f * acc[di][dj];
      }
    __syncthreads();
    int tmp = pa; pa = pc; pc = tmp;
  }
  const float sr = sqrtf(r);
  // wm -> bf16 hi/lo split, stored in MFMA A-frag order: [row][P] with
  // channel c = 4*(P&15) + (P>>4)  (k_apply's K-permutation)
  for (int idx = t; idx < 4096; idx += 256) {
    int row = idx >> 6, P = idx & 63;
    int c = 4 * (P & 15) + (P >> 4);
    float f = bufs[pa][row][c] * sr;
    unsigned short hi = f2bf(f);
    unsigned short lo = f2bf(f - bf2f(hi));
    wmh[idx] = hi;
    wml[idx] = lo;
  }
  if (t < 64) {
    float a = 0.f;
    for (int k = 0; k < 64; ++k) a += bufs[pa][t][k] * mean_s[k];
    bias[t] = -a * sr;
  }
}

// ---------------- Pass 3: out = wm*x + bias via MFMA, transposed LDS -----------
// K-permutation: position P <-> channel c = 4*(P&15) + (P>>4); A and B both use
// it, so the contraction is exact. wm hi/lo frags preformatted by k_ns.
__global__ __launch_bounds__(256) void k_apply(const float* __restrict__ x,
                                               const float* __restrict__ ws,
                                               float* __restrict__ out) {
  __shared__ unsigned short Y[256][68];   // [pixel][P], row 136 B (8B-aligned)
  const int t    = threadIdx.x;
  const int lane = t & 63;
  const int wv   = t >> 6;
  const int g    = lane >> 4;
  const int m    = lane & 15;
  const int bx   = blockIdx.x;
  const int b    = bx / TILES_PER_B;
  const int p0   = (bx - b * TILES_PER_B) * 256;
  const unsigned short* __restrict__ wmh = (const unsigned short*)(ws + WS_WMH);
  const unsigned short* __restrict__ wml = (const unsigned short*)(ws + WS_WML);
  const float* __restrict__ bias = ws + WS_BIAS;

  // ---- A-frags: preformatted, 4x 16B loads (L2-hot)
  const int arow = wv * 16 + m;
  bf16x8_t aHi[2], aLo[2];
  #pragma unroll
  for (int ks = 0; ks < 2; ++ks) {
    aHi[ks] = *(const bf16x8_t*)&wmh[arow * 64 + ks * 32 + g * 8];
    aLo[ks] = *(const bf16x8_t*)&wml[arow * 64 + ks * 32 + g * 8];
  }
  float bv[4];
  #pragma unroll
  for (int rr = 0; rr < 4; ++rr) bv[rr] = bias[wv * 16 + g * 4 + rr];

  // ---- stage: thread t owns pixel p0+t, loads 64 channels as scalar dwords
  const size_t gbase = (size_t)(b * 64) * HW_PIX + p0 + t;
  #pragma unroll
  for (int r = 0; r < 4; ++r) {
    float f[16];
    #pragma unroll
    for (int j = 0; j < 16; ++j)
      f[j] = x[gbase + (size_t)(4 * j + r) * HW_PIX];
    #pragma unroll
    for (int q = 0; q < 4; ++q) {
      ushort4 u;
      u.x = f2bf(f[4 * q + 0]); u.y = f2bf(f[4 * q + 1]);
      u.z = f2bf(f[4 * q + 2]); u.w = f2bf(f[4 * q + 3]);
      *(ushort4*)&Y[t][16 * r + 4 * q] = u;   // P = 16r + 4q + e
    }
  }
  __syncthreads();

  // ---- MFMA: wave wv owns out rows [wv*16, wv*16+16), 16 pixel-tiles
  const size_t obase = (size_t)(b * 64) * HW_PIX + p0;
  #pragma unroll 2
  for (int tile = 0; tile < 16; ++tile) {
    const int pcol = tile * 16 + m;
    bf16x8_t bf[2];
    #pragma unroll
    for (int ks = 0; ks < 2; ++ks) {
      union { ushort4 u2[2]; bf16x8_t v; } cu;
      cu.u2[0] = *(const ushort4*)&Y[pcol][ks * 32 + g * 8];
      cu.u2[1] = *(const ushort4*)&Y[pcol][ks * 32 + g * 8 + 4];
      bf[ks] = cu.v;
    }
    f32x4_t acc = (f32x4_t){bv[0], bv[1], bv[2], bv[3]};
    acc = __builtin_amdgcn_mfma_f32_16x16x32_bf16(aHi[0], bf[0], acc, 0, 0, 0);
    acc = __builtin_amdgcn_mfma_f32_16x16x32_bf16(aHi[1], bf[1], acc, 0, 0, 0);
    acc = __builtin_amdgcn_mfma_f32_16x16x32_bf16(aLo[0], bf[0], acc, 0, 0, 0);
    acc = __builtin_amdgcn_mfma_f32_16x16x32_bf16(aLo[1], bf[1], acc, 0, 0, 0);
    // D map: col = lane&15, row = (lane>>4)*4 + reg
    #pragma unroll
    for (int rr = 0; rr < 4; ++rr)
      out[obase + (size_t)(wv * 16 + g * 4 + rr) * HW_PIX + tile * 16 + m] = acc[rr];
  }
}

extern "C" void kernel_launch(void* const* d_in, const int* in_sizes, int n_in,
                              void* d_out, int out_size, void* d_ws, size_t ws_size,
                              hipStream_t stream) {
  const float* x = (const float*)d_in[0];
  float* out = (float*)d_out;
  float* ws  = (float*)d_ws;
  hipMemsetAsync(d_ws, 0, (32768 + 512) * sizeof(float), stream);  // G8 + S8
  k_gram<<<GRID1, 256, 0, stream>>>(x, ws);
  k_ns<<<1, 256, 0, stream>>>(ws);
  k_apply<<<NTILE, 256, 0, stream>>>(x, ws, out);
}